// Round 1
// baseline (424.436 us; speedup 1.0000x reference)
//
#include <hip/hip_runtime.h>
#include <hip/hip_bf16.h>

// Workspace float slots:
// 0: cls_loss  1: noobj  2: S0(count obj)  3: S1_p0  4: S2_p0  5: S1_p1  6: S2_p1
// 7: reg_p0    8: reg_p1          int slot after: [9] = max obj index
#define NQ 9

__global__ __launch_bounds__(256) void yolo_main_kernel(
    const float* __restrict__ pred,
    const float* __restrict__ tbox,
    const float* __restrict__ tcls,
    const int*   __restrict__ obj,
    float* __restrict__ ws_f,
    int*   __restrict__ ws_i,
    int M)
{
    float acc[NQ];
#pragma unroll
    for (int q = 0; q < NQ; ++q) acc[q] = 0.f;
    int imax = -1;

    const int tid    = blockIdx.x * blockDim.x + threadIdx.x;
    const int stride = gridDim.x * blockDim.x;

    for (int cell = tid; cell < M; cell += stride) {
        // pred cell: 30 floats, byte offset cell*120 -> 8B aligned -> float2 x15
        const float2* p2 = reinterpret_cast<const float2*>(pred + (size_t)cell * 30);
        float pr[30];
#pragma unroll
        for (int j = 0; j < 15; ++j) {
            float2 v = p2[j];
            pr[2 * j] = v.x;
            pr[2 * j + 1] = v.y;
        }
        // target_cls cell: 20 floats, byte offset cell*80 -> 16B aligned -> float4 x5
        const float4* c4 = reinterpret_cast<const float4*>(tcls + (size_t)cell * 20);
        float tc[20];
#pragma unroll
        for (int j = 0; j < 5; ++j) {
            float4 v = c4[j];
            tc[4 * j] = v.x; tc[4 * j + 1] = v.y; tc[4 * j + 2] = v.z; tc[4 * j + 3] = v.w;
        }
        float cl = 0.f;
#pragma unroll
        for (int k = 0; k < 20; ++k) {
            float d = pr[10 + k] - tc[k];
            cl += d * d;
        }
        acc[0] += cl;

        const bool  o   = (obj[cell] != 0);
        const float p0c = pr[4];
        if (!o) {
            acc[1] += p0c * p0c;   // L_NOOBJ * 2 == 1.0
        } else {
            float4 t = reinterpret_cast<const float4*>(tbox)[cell];
            acc[2] += 1.f;
            acc[3] += p0c;
            acc[4] += p0c * p0c;
            const float p1c = pr[9];
            acc[5] += p1c;
            acc[6] += p1c * p1c;
            const float st2 = sqrtf(t.z), st3 = sqrtf(t.w);
            {
                float dx = pr[0] - t.x, dy = pr[1] - t.y;
                float dw = sqrtf(pr[2]) - st2, dh = sqrtf(pr[3]) - st3;
                acc[7] += dx * dx + dy * dy + dw * dw + dh * dh;
            }
            {
                float dx = pr[5] - t.x, dy = pr[6] - t.y;
                float dw = sqrtf(pr[7]) - st2, dh = sqrtf(pr[8]) - st3;
                acc[8] += dx * dx + dy * dy + dw * dw + dh * dh;
            }
            imax = max(imax, cell);
        }
    }

    // wave (64-lane) shuffle reduction
#pragma unroll
    for (int off = 32; off > 0; off >>= 1) {
#pragma unroll
        for (int q = 0; q < NQ; ++q) acc[q] += __shfl_down(acc[q], off, 64);
        imax = max(imax, __shfl_down(imax, off, 64));
    }

    __shared__ float sred[4][NQ];
    __shared__ int   sidx[4];
    const int lane = threadIdx.x & 63;
    const int wid  = threadIdx.x >> 6;
    if (lane == 0) {
#pragma unroll
        for (int q = 0; q < NQ; ++q) sred[wid][q] = acc[q];
        sidx[wid] = imax;
    }
    __syncthreads();
    if (threadIdx.x == 0) {
        float tot[NQ];
        int   mx = sidx[0];
#pragma unroll
        for (int q = 0; q < NQ; ++q) tot[q] = sred[0][q];
        for (int w = 1; w < 4; ++w) {
#pragma unroll
            for (int q = 0; q < NQ; ++q) tot[q] += sred[w][q];
            mx = max(mx, sidx[w]);
        }
#pragma unroll
        for (int q = 0; q < NQ; ++q) atomicAdd(&ws_f[q], tot[q]);
        atomicMax(ws_i, mx);
    }
}

__global__ void yolo_final_kernel(const float* __restrict__ pred,
                                  const float* __restrict__ tbox,
                                  const float* __restrict__ ws_f,
                                  const int*   __restrict__ ws_i,
                                  float* __restrict__ out,
                                  float invN)
{
    if (threadIdx.x != 0 || blockIdx.x != 0) return;
    const int idx = ws_i[0];
    const float* p = pred + (size_t)idx * 30;
    const float* t = tbox + (size_t)idx * 4;

    auto mkxyxy = [](float x, float y, float w, float h, float* o) {
        float cx = x / 14.f, cy = y / 14.f;
        o[0] = cx - 0.5f * w; o[1] = cy - 0.5f * h;
        o[2] = cx + 0.5f * w; o[3] = cy + 0.5f * h;
    };
    float b0[4], b1[4], bt[4];
    mkxyxy(p[0], p[1], p[2], p[3], b0);
    mkxyxy(p[5], p[6], p[7], p[8], b1);
    mkxyxy(t[0], t[1], t[2], t[3], bt);

    auto iou = [](const float* a, const float* b) {
        float ltx = fmaxf(a[0], b[0]), lty = fmaxf(a[1], b[1]);
        float rbx = fminf(a[2], b[2]), rby = fminf(a[3], b[3]);
        float w = fmaxf(rbx - ltx, 0.f), h = fmaxf(rby - lty, 0.f);
        float inter = w * h;
        float a1 = (a[2] - a[0]) * (a[3] - a[1]);
        float a2 = (b[2] - b[0]) * (b[3] - b[1]);
        return inter / (a1 + a2 - inter);
    };
    float iou0 = iou(b0, bt), iou1 = iou(b1, bt);
    bool  m = iou0 > iou1;
    float c = m ? iou0 : iou1;

    float S0  = ws_f[2];
    float S1  = m ? ws_f[3] : ws_f[5];
    float S2  = m ? ws_f[4] : ws_f[6];
    float reg = m ? ws_f[7] : ws_f[8];

    float reg_loss   = 5.f * reg;                       // L_COORD
    float containing = S2 - 2.f * c * S1 + c * c * S0;  // sum obj*(conf - c)^2
    float noobj      = ws_f[1];
    float cls        = ws_f[0];
    float total      = cls + noobj + reg_loss + containing;

    out[0] = total * invN;
    out[1] = reg_loss * invN;
    out[2] = containing * invN;
    out[3] = noobj * invN;
    out[4] = cls * invN;
}

extern "C" void kernel_launch(void* const* d_in, const int* in_sizes, int n_in,
                              void* d_out, int out_size, void* d_ws, size_t ws_size,
                              hipStream_t stream) {
    const float* pred = (const float*)d_in[0];
    const float* tbox = (const float*)d_in[1];
    const float* tcls = (const float*)d_in[2];
    const int*   obj  = (const int*)d_in[3];
    float* out = (float*)d_out;

    const int M = in_sizes[3];                  // BATCH * S * S
    const int N = in_sizes[0] / (14 * 14 * 30); // BATCH

    float* ws_f = (float*)d_ws;
    int*   ws_i = (int*)d_ws + NQ;

    // harness poisons d_ws to 0xAA before every launch -> must zero each call
    hipMemsetAsync(d_ws, 0, (NQ + 1) * sizeof(float), stream);

    const int threads = 256;
    int blocks = (M + threads - 1) / threads;
    if (blocks > 2048) blocks = 2048;
    yolo_main_kernel<<<blocks, threads, 0, stream>>>(pred, tbox, tcls, obj, ws_f, ws_i, M);
    yolo_final_kernel<<<1, 64, 0, stream>>>(pred, tbox, ws_f, ws_i, out, 1.f / (float)N);
}